// Round 1
// baseline (802.638 us; speedup 1.0000x reference)
//
#include <hip/hip_runtime.h>
#include <math.h>

// Problem constants
#define TC 256            // crop T
#define HC 128            // spatial H=W
#define Z2 512            // 2*T
#define Y2 256            // 2*H
#define X2 256            // 2*W
#define XS 129            // stored spectral x bins (Hermitian half)
#define XP 130            // padded x stride (float2 elems)
#define HW 16384          // HC*HC
#define LSTR256 260       // LDS line stride for 256-pt lines (float2)
#define LSTR512 519       // LDS line stride for 512-pt lines (float2)

__device__ __forceinline__ float2 cadd(float2 a, float2 b){ return make_float2(a.x+b.x, a.y+b.y); }
__device__ __forceinline__ float2 csub(float2 a, float2 b){ return make_float2(a.x-b.x, a.y-b.y); }

// w stored as e^{-2*pi*i*j/N}. SGN=-1 uses w as-is (forward), SGN=+1 uses conj(w) (inverse).
template<int SGN>
__device__ __forceinline__ float2 cmul_tw(float2 z, float2 w){
  float wy = (SGN < 0) ? w.y : -w.y;
  return make_float2(z.x*w.x - z.y*wy, z.x*wy + z.y*w.x);
}
// SGN=-1: multiply by -i ; SGN=+1: multiply by +i
template<int SGN>
__device__ __forceinline__ float2 mul_pmi(float2 t){
  return (SGN < 0) ? make_float2(t.y, -t.x) : make_float2(-t.y, t.x);
}

// In-register 16-point DFT: r[k] = sum_j r_in[j] * W16^{j*k*SGN-dir}
// tw = tw256 table (W16^m == tw256[16m])
template<int SGN>
__device__ __forceinline__ void dft16(float2 r[16], const float2* __restrict__ tw){
  float2 u[16];
  #pragma unroll
  for (int b2=0;b2<4;b2++){
    float2 x0=r[b2], x1=r[4+b2], x2=r[8+b2], x3=r[12+b2];
    float2 t0=cadd(x0,x2), t1=csub(x0,x2), t2=cadd(x1,x3), t3=csub(x1,x3);
    float2 y0=cadd(t0,t2), y2=csub(t0,t2);
    float2 t3i = mul_pmi<SGN>(t3);
    float2 y1=cadd(t1,t3i), y3=csub(t1,t3i);
    u[0*4+b2]=y0;
    u[1*4+b2]=cmul_tw<SGN>(y1, tw[(16*b2)&255]);
    u[2*4+b2]=cmul_tw<SGN>(y2, tw[(32*b2)&255]);
    u[3*4+b2]=cmul_tw<SGN>(y3, tw[(48*b2)&255]);
  }
  #pragma unroll
  for (int e2=0;e2<4;e2++){
    float2 x0=u[e2*4+0], x1=u[e2*4+1], x2=u[e2*4+2], x3=u[e2*4+3];
    float2 t0=cadd(x0,x2), t1=csub(x0,x2), t2=cadd(x1,x3), t3=csub(x1,x3);
    float2 t3i = mul_pmi<SGN>(t3);
    r[0*4+e2]=cadd(t0,t2);
    r[1*4+e2]=cadd(t1,t3i);
    r[2*4+e2]=csub(t0,t2);
    r[3*4+e2]=csub(t1,t3i);
  }
}

// 256-pt FFT on one LDS line (contiguous 256 float2 at ln), 16 threads/line, b = lane-in-line.
// Caller must __syncthreads() after filling ln. Result left in ln (natural order).
template<int SGN>
__device__ __forceinline__ void fft256(float2* ln, int b, const float2* __restrict__ tw){
  float2 r[16];
  #pragma unroll
  for (int a=0;a<16;a++) r[a] = ln[16*a+b];
  dft16<SGN>(r, tw);
  #pragma unroll
  for (int e=1;e<16;e++) r[e] = cmul_tw<SGN>(r[e], tw[(b*e)&255]);
  __syncthreads();
  #pragma unroll
  for (int e=0;e<16;e++) ln[16*e+b] = r[e];
  __syncthreads();
  #pragma unroll
  for (int a=0;a<16;a++) r[a] = ln[16*b+a];
  dft16<SGN>(r, tw);
  __syncthreads();
  #pragma unroll
  for (int d=0;d<16;d++) ln[16*d+b] = r[d];
  __syncthreads();
}

// 512-pt FFT on one LDS line (contiguous 512 float2 at ln), 32 threads/line, lt in [0,32).
// Even/odd split into two 256-pt FFTs + combine. If CROP_OUT, only outputs n<256 are valid in ln.
template<int SGN, bool CROP_OUT>
__device__ __forceinline__ void fft512(float2* ln, int lt,
        const float2* __restrict__ tw256, const float2* __restrict__ tw512){
  int team = lt >> 4, b = lt & 15;
  float2* sc = ln + team*256;
  float2 r[16];
  #pragma unroll
  for (int a=0;a<16;a++) r[a] = ln[2*(16*a+b) + team];
  dft16<SGN>(r, tw256);
  #pragma unroll
  for (int e=1;e<16;e++) r[e] = cmul_tw<SGN>(r[e], tw256[(b*e)&255]);
  __syncthreads();
  #pragma unroll
  for (int e=0;e<16;e++) sc[16*e+b] = r[e];
  __syncthreads();
  #pragma unroll
  for (int a=0;a<16;a++) r[a] = sc[16*b+a];
  dft16<SGN>(r, tw256);
  __syncthreads();
  if (team==0){
    #pragma unroll
    for (int d=0;d<16;d++) ln[16*d+b] = r[d];
  } else {
    #pragma unroll
    for (int d=0;d<16;d++){ int k=16*d+b; ln[256+k] = cmul_tw<SGN>(r[d], tw512[k]); }
  }
  __syncthreads();
  float2 res[8], res2[8];
  #pragma unroll
  for (int j=0;j<8;j++){
    int k = lt + 32*j;
    float2 E = ln[k], WO = ln[256+k];
    res[j]  = cadd(E,WO);
    res2[j] = csub(E,WO);
  }
  __syncthreads();
  #pragma unroll
  for (int j=0;j<8;j++){
    int k = lt + 32*j;
    ln[k] = res[j];
    if (!CROP_OUT) ln[256+k] = res2[j];
  }
  __syncthreads();
}

// ---------------- twiddle init ----------------
__global__ void k_init_tw(float2* tw256, float2* tw512){
  int j = threadIdx.x;  // 512 threads
  if (j < 512){
    double a = -6.283185307179586476925286766559 * (double)j / 512.0;
    tw512[j] = make_float2((float)cos(a), (float)sin(a));
  }
  if (j < 256){
    double a = -6.283185307179586476925286766559 * (double)j / 256.0;
    tw256[j] = make_float2((float)cos(a), (float)sin(a));
  }
}

// ---------------- GEMM: C[m][hw] = sum_t A[m][t] * B[t][hw] * (gz? gz[t]^4 : 1) ----------------
__global__ __launch_bounds__(256) void k_gemm(const float* __restrict__ A,
    const float* __restrict__ Bv, const float* __restrict__ gz, float* __restrict__ C){
  __shared__ float As[64][64];   // [tt][mi]
  __shared__ float zz[64];
  int tid = threadIdx.x;
  int hw = blockIdx.x*256 + tid;
  int m0 = blockIdx.y*64;
  float acc[64];
  #pragma unroll
  for (int i=0;i<64;i++) acc[i]=0.f;
  for (int t0=0;t0<256;t0+=64){
    __syncthreads();
    #pragma unroll
    for (int e=0;e<16;e++){
      int tt = e*4 + (tid>>6);
      int mi = tid & 63;
      As[tt][mi] = A[(size_t)(m0+mi)*256 + t0 + tt];
    }
    if (tid < 64){
      float s = 1.f;
      if (gz){ float g = gz[t0+tid]; float g2=g*g; s = g2*g2; }
      zz[tid] = s;
    }
    __syncthreads();
    for (int tt=0;tt<64;tt++){
      float v = Bv[(size_t)(t0+tt)*HW + hw] * zz[tt];
      const float4* row = (const float4*)&As[tt][0];
      #pragma unroll
      for (int q=0;q<16;q++){
        float4 a4 = row[q];
        acc[4*q+0] += a4.x*v; acc[4*q+1] += a4.y*v;
        acc[4*q+2] += a4.z*v; acc[4*q+3] += a4.w*v;
      }
    }
  }
  #pragma unroll
  for (int mi=0;mi<64;mi++) C[(size_t)(m0+mi)*HW + hw] = acc[mi];
}

// ---------------- Pass 1: R2C along x (zero-pad 128->256), lines (m<256, y<128) ----------------
__global__ __launch_bounds__(256) void k_fft_x_fwd(const float* __restrict__ tmp,
     float2* __restrict__ S, const float2* __restrict__ tw256){
  __shared__ float2 buf[16*LSTR256];
  int tid = threadIdx.x;
  int w = tid >> 4, b = tid & 15;
  int line = blockIdx.x*16 + w;       // 32768 lines
  int m = line >> 7, y = line & 127;
  float2* ln = buf + w*LSTR256;
  const float* src = tmp + (size_t)(m*128 + y)*128;
  #pragma unroll
  for (int a=0;a<16;a++){
    int n = 16*a + b;
    ln[n] = make_float2((n<128)? src[n] : 0.f, 0.f);
  }
  __syncthreads();
  fft256<-1>(ln, b, tw256);
  float2* dst = S + ((size_t)m*256 + y)*XP;
  #pragma unroll
  for (int a=0;a<8;a++){
    int k = 16*a + b;
    dst[k] = ln[k];
  }
  if (b==0) dst[128] = ln[128];
}

// ---------------- Pass 2: fwd along y (z<256), input y<128 nonzero, x<129 ----------------
__global__ __launch_bounds__(256) void k_fft_y_fwd(float2* __restrict__ S, const float2* __restrict__ tw256){
  __shared__ float2 buf[16*LSTR256];
  int tid = threadIdx.x;
  int w = tid & 15, b = tid >> 4;
  int z = blockIdx.x;               // 0..255
  int x = blockIdx.y*16 + w;        // up to 143
  bool act = (x < XS);
  float2* ln = buf + w*LSTR256;
  size_t base = ((size_t)z*256)*XP + x;
  #pragma unroll
  for (int a=0;a<8;a++){
    int n = 16*a + b;   // y 0..127
    ln[n] = act ? S[base + (size_t)n*XP] : make_float2(0.f,0.f);
    ln[n+128] = make_float2(0.f,0.f);
  }
  __syncthreads();
  fft256<-1>(ln, b, tw256);
  #pragma unroll
  for (int a=0;a<16;a++){
    int n = 16*a + b;
    if (act) S[base + (size_t)n*XP] = ln[n];
  }
}

// ---------------- Pass 3: fwd along z, L=512, input z<256 nonzero ----------------
__global__ __launch_bounds__(256) void k_fft_z_fwd(float2* __restrict__ S,
      const float2* __restrict__ tw256, const float2* __restrict__ tw512){
  __shared__ float2 buf[8*LSTR512];
  int tid = threadIdx.x;
  int w = tid & 7, lt = tid >> 3;
  int y = blockIdx.x;               // 0..255
  int x = blockIdx.y*8 + w;         // up to 135
  bool act = (x < XS);
  float2* ln = buf + w*LSTR512;
  size_t base = (size_t)y*XP + x;
  #pragma unroll
  for (int a=0;a<16;a++){
    int n = 32*a + lt;
    ln[n] = (act && n<256) ? S[base + (size_t)n*256*XP] : make_float2(0.f,0.f);
  }
  __syncthreads();
  fft512<-1,false>(ln, lt, tw256, tw512);
  #pragma unroll
  for (int a=0;a<16;a++){
    int n = 32*a + lt;
    if (act) S[base + (size_t)n*256*XP] = ln[n];
  }
}

// ---------------- Pass 4: pointwise Hermitian-symmetrized filter + 1/N ----------------
__global__ __launch_bounds__(256) void k_filter(float2* __restrict__ S, const float* __restrict__ R,
    const float* __restrict__ I, const float* __restrict__ w0, const float* __restrict__ w1){
  size_t idx = (size_t)blockIdx.x*256 + threadIdx.x;
  const size_t NPT = (size_t)Z2*Y2*XS;
  if (idx >= NPT) return;
  unsigned x  = (unsigned)(idx % XS);
  unsigned r2 = (unsigned)(idx / XS);
  unsigned ky = r2 & 255u;
  unsigned kz = r2 >> 8;
  unsigned mx = (256u - x) & 255u;
  unsigned my = (256u - ky) & 255u;
  unsigned mz = (512u - kz) & 511u;
  size_t ik  = ((size_t)kz*256 + ky)*256 + x;
  size_t imk = ((size_t)mz*256 + my)*256 + mx;
  float wr = R[ik] + 0.5f*(w0[ik] + w0[imk]);
  float wi = I[ik] + 0.5f*(w1[ik] - w1[imk]);
  const float sc = 1.f/33554432.f;   // 1/(512*256*256)
  wr *= sc; wi *= sc;
  size_t is = ((size_t)kz*256 + ky)*XP + x;
  float2 v = S[is];
  S[is] = make_float2(v.x*wr - v.y*wi, v.x*wi + v.y*wr);
}

// ---------------- Pass 5: inv along z, L=512, keep z<256 ----------------
__global__ __launch_bounds__(256) void k_fft_z_inv(float2* __restrict__ S,
      const float2* __restrict__ tw256, const float2* __restrict__ tw512){
  __shared__ float2 buf[8*LSTR512];
  int tid = threadIdx.x;
  int w = tid & 7, lt = tid >> 3;
  int y = blockIdx.x;
  int x = blockIdx.y*8 + w;
  bool act = (x < XS);
  float2* ln = buf + w*LSTR512;
  size_t base = (size_t)y*XP + x;
  #pragma unroll
  for (int a=0;a<16;a++){
    int n = 32*a + lt;
    ln[n] = act ? S[base + (size_t)n*256*XP] : make_float2(0.f,0.f);
  }
  __syncthreads();
  fft512<1,true>(ln, lt, tw256, tw512);
  #pragma unroll
  for (int a=0;a<8;a++){
    int n = 32*a + lt;   // 0..255
    if (act) S[base + (size_t)n*256*XP] = ln[n];
  }
}

// ---------------- Pass 6: inv along y (z<256), keep y<128 ----------------
__global__ __launch_bounds__(256) void k_fft_y_inv(float2* __restrict__ S, const float2* __restrict__ tw256){
  __shared__ float2 buf[16*LSTR256];
  int tid = threadIdx.x;
  int w = tid & 15, b = tid >> 4;
  int z = blockIdx.x;       // t 0..255
  int x = blockIdx.y*16 + w;
  bool act = (x < XS);
  float2* ln = buf + w*LSTR256;
  size_t base = ((size_t)z*256)*XP + x;
  #pragma unroll
  for (int a=0;a<16;a++){
    int n = 16*a + b;
    ln[n] = act ? S[base + (size_t)n*XP] : make_float2(0.f,0.f);
  }
  __syncthreads();
  fft256<1>(ln, b, tw256);
  #pragma unroll
  for (int a=0;a<8;a++){
    int n = 16*a + b;    // 0..127
    if (act) S[base + (size_t)n*XP] = ln[n];
  }
}

// ---------------- Pass 7: inv C2R along x, keep x<128, write real vol ----------------
__global__ __launch_bounds__(256) void k_fft_x_inv(const float2* __restrict__ S,
      float* __restrict__ vol, const float2* __restrict__ tw256){
  __shared__ float2 buf[16*LSTR256];
  int tid = threadIdx.x;
  int w = tid >> 4, b = tid & 15;
  int line = blockIdx.x*16 + w;   // t*128 + y
  int t = line >> 7, y = line & 127;
  float2* ln = buf + w*LSTR256;
  const float2* src = S + ((size_t)t*256 + y)*XP;
  #pragma unroll
  for (int a=0;a<8;a++){
    int k = 16*a + b;
    ln[k] = src[k];
  }
  if (b==0) ln[128] = src[128];
  __syncthreads();
  #pragma unroll
  for (int a=8;a<16;a++){
    int k = 16*a + b;     // 128..255
    if (k > 128){ float2 v = ln[256-k]; ln[k] = make_float2(v.x, -v.y); }
  }
  __syncthreads();
  fft256<1>(ln, b, tw256);
  float* dst = vol + (size_t)(t*128 + y)*128;
  #pragma unroll
  for (int a=0;a<8;a++){
    int n = 16*a + b;
    dst[n] = ln[n].x;
  }
}

extern "C" void kernel_launch(void* const* d_in, const int* in_sizes, int n_in,
                              void* d_out, int out_size, void* d_ws, size_t ws_size,
                              hipStream_t stream) {
  const float* fet = (const float*)d_in[0];           // (1,1,256,128,128)
  const float* gz  = (const float*)d_in[1];           // (1,256,1,1)
  const float* mtx = (const float*)d_in[2];           // (256,256)
  const float* mtxi= (const float*)d_in[3];           // (256,256)
  const float* Rr  = (const float*)d_in[4];           // (512,256,256)
  const float* Ii  = (const float*)d_in[5];           // (512,256,256)
  const float* lw  = (const float*)d_in[6];           // (2,512,256,256)
  const float* w0  = lw;
  const float* w1  = lw + (size_t)Z2*Y2*X2;
  float* out = (float*)d_out;

  char* ws = (char*)d_ws;
  const size_t OFF_TW256 = 0;
  const size_t OFF_TW512 = 2048;
  const size_t OFF_S     = 8192;
  const size_t S_BYTES   = (size_t)Z2*Y2*XP*sizeof(float2);   // 136,314,880
  const size_t OFF_TMP   = OFF_S + S_BYTES;
  const size_t OFF_VOL   = OFF_TMP + (size_t)TC*HW*sizeof(float);
  const size_t NEED      = OFF_VOL + (size_t)TC*HW*sizeof(float);
  if (ws_size < NEED) return;   // diagnostic: leaves d_out zero

  float2* tw256 = (float2*)(ws + OFF_TW256);
  float2* tw512 = (float2*)(ws + OFF_TW512);
  float2* S     = (float2*)(ws + OFF_S);
  float*  tmp   = (float*)(ws + OFF_TMP);
  float*  vol   = (float*)(ws + OFF_VOL);

  hipLaunchKernelGGL(k_init_tw, dim3(1), dim3(512), 0, stream, tw256, tw512);
  hipLaunchKernelGGL(k_gemm, dim3(64,4), dim3(256), 0, stream, mtx, fet, gz, tmp);
  hipLaunchKernelGGL(k_fft_x_fwd, dim3(2048), dim3(256), 0, stream, tmp, S, tw256);
  hipLaunchKernelGGL(k_fft_y_fwd, dim3(256,9), dim3(256), 0, stream, S, tw256);
  hipLaunchKernelGGL(k_fft_z_fwd, dim3(256,17), dim3(256), 0, stream, S, tw256, tw512);
  hipLaunchKernelGGL(k_filter, dim3(66048), dim3(256), 0, stream, S, Rr, Ii, w0, w1);
  hipLaunchKernelGGL(k_fft_z_inv, dim3(256,17), dim3(256), 0, stream, S, tw256, tw512);
  hipLaunchKernelGGL(k_fft_y_inv, dim3(256,9), dim3(256), 0, stream, S, tw256);
  hipLaunchKernelGGL(k_fft_x_inv, dim3(2048), dim3(256), 0, stream, S, vol, tw256);
  hipLaunchKernelGGL(k_gemm, dim3(64,4), dim3(256), 0, stream, mtxi, vol, (const float*)nullptr, out);
}

// Round 2
// 490.395 us; speedup vs baseline: 1.6367x; 1.6367x over previous
//
#include <hip/hip_runtime.h>
#include <math.h>

// Problem constants
#define TC 256            // crop T
#define HC 128            // spatial H=W
#define Z2 512            // 2*T
#define Y2 256            // 2*H
#define X2 256            // 2*W
#define XS 129            // stored spectral x bins (Hermitian half)
#define XP 130            // padded x stride (float2 elems)
#define HW 16384          // HC*HC
#define LSTR256 260       // LDS line stride for 256-pt lines (float2)
#define LSTR512 519       // LDS line stride for 512-pt lines (float2)
#define MT 32             // per-thread m-tile in GEMM

__device__ __forceinline__ float2 cadd(float2 a, float2 b){ return make_float2(a.x+b.x, a.y+b.y); }
__device__ __forceinline__ float2 csub(float2 a, float2 b){ return make_float2(a.x-b.x, a.y-b.y); }

// w stored as e^{-2*pi*i*j/N}. SGN=-1 uses w as-is (forward), SGN=+1 uses conj(w) (inverse).
template<int SGN>
__device__ __forceinline__ float2 cmul_tw(float2 z, float2 w){
  float wy = (SGN < 0) ? w.y : -w.y;
  return make_float2(z.x*w.x - z.y*wy, z.x*wy + z.y*w.x);
}
// SGN=-1: multiply by -i ; SGN=+1: multiply by +i
template<int SGN>
__device__ __forceinline__ float2 mul_pmi(float2 t){
  return (SGN < 0) ? make_float2(t.y, -t.x) : make_float2(-t.y, t.x);
}

// In-register 16-point DFT: r[k] = sum_j r_in[j] * W16^{j*k*SGN-dir}
template<int SGN>
__device__ __forceinline__ void dft16(float2 r[16], const float2* __restrict__ tw){
  float2 u[16];
  #pragma unroll
  for (int b2=0;b2<4;b2++){
    float2 x0=r[b2], x1=r[4+b2], x2=r[8+b2], x3=r[12+b2];
    float2 t0=cadd(x0,x2), t1=csub(x0,x2), t2=cadd(x1,x3), t3=csub(x1,x3);
    float2 y0=cadd(t0,t2), y2=csub(t0,t2);
    float2 t3i = mul_pmi<SGN>(t3);
    float2 y1=cadd(t1,t3i), y3=csub(t1,t3i);
    u[0*4+b2]=y0;
    u[1*4+b2]=cmul_tw<SGN>(y1, tw[(16*b2)&255]);
    u[2*4+b2]=cmul_tw<SGN>(y2, tw[(32*b2)&255]);
    u[3*4+b2]=cmul_tw<SGN>(y3, tw[(48*b2)&255]);
  }
  #pragma unroll
  for (int e2=0;e2<4;e2++){
    float2 x0=u[e2*4+0], x1=u[e2*4+1], x2=u[e2*4+2], x3=u[e2*4+3];
    float2 t0=cadd(x0,x2), t1=csub(x0,x2), t2=cadd(x1,x3), t3=csub(x1,x3);
    float2 t3i = mul_pmi<SGN>(t3);
    r[0*4+e2]=cadd(t0,t2);
    r[1*4+e2]=cadd(t1,t3i);
    r[2*4+e2]=csub(t0,t2);
    r[3*4+e2]=csub(t1,t3i);
  }
}

// 256-pt FFT on one LDS line (contiguous 256 float2 at ln), 16 threads/line, b = lane-in-line.
template<int SGN>
__device__ __forceinline__ void fft256(float2* ln, int b, const float2* __restrict__ tw){
  float2 r[16];
  #pragma unroll
  for (int a=0;a<16;a++) r[a] = ln[16*a+b];
  dft16<SGN>(r, tw);
  #pragma unroll
  for (int e=1;e<16;e++) r[e] = cmul_tw<SGN>(r[e], tw[(b*e)&255]);
  __syncthreads();
  #pragma unroll
  for (int e=0;e<16;e++) ln[16*e+b] = r[e];
  __syncthreads();
  #pragma unroll
  for (int a=0;a<16;a++) r[a] = ln[16*b+a];
  dft16<SGN>(r, tw);
  __syncthreads();
  #pragma unroll
  for (int d=0;d<16;d++) ln[16*d+b] = r[d];
  __syncthreads();
}

// 512-pt FFT on one LDS line (contiguous 512 float2 at ln), 32 threads/line, lt in [0,32).
template<int SGN, bool CROP_OUT>
__device__ __forceinline__ void fft512(float2* ln, int lt,
        const float2* __restrict__ tw256, const float2* __restrict__ tw512){
  int team = lt >> 4, b = lt & 15;
  float2* sc = ln + team*256;
  float2 r[16];
  #pragma unroll
  for (int a=0;a<16;a++) r[a] = ln[2*(16*a+b) + team];
  dft16<SGN>(r, tw256);
  #pragma unroll
  for (int e=1;e<16;e++) r[e] = cmul_tw<SGN>(r[e], tw256[(b*e)&255]);
  __syncthreads();
  #pragma unroll
  for (int e=0;e<16;e++) sc[16*e+b] = r[e];
  __syncthreads();
  #pragma unroll
  for (int a=0;a<16;a++) r[a] = sc[16*b+a];
  dft16<SGN>(r, tw256);
  __syncthreads();
  if (team==0){
    #pragma unroll
    for (int d=0;d<16;d++) ln[16*d+b] = r[d];
  } else {
    #pragma unroll
    for (int d=0;d<16;d++){ int k=16*d+b; ln[256+k] = cmul_tw<SGN>(r[d], tw512[k]); }
  }
  __syncthreads();
  float2 res[8], res2[8];
  #pragma unroll
  for (int j=0;j<8;j++){
    int k = lt + 32*j;
    float2 E = ln[k], WO = ln[256+k];
    res[j]  = cadd(E,WO);
    res2[j] = csub(E,WO);
  }
  __syncthreads();
  #pragma unroll
  for (int j=0;j<8;j++){
    int k = lt + 32*j;
    ln[k] = res[j];
    if (!CROP_OUT) ln[256+k] = res2[j];
  }
  __syncthreads();
}

// ---------------- twiddle init ----------------
__global__ void k_init_tw(float2* tw256, float2* tw512){
  int j = threadIdx.x;  // 512 threads
  if (j < 512){
    double a = -6.283185307179586476925286766559 * (double)j / 512.0;
    tw512[j] = make_float2((float)cos(a), (float)sin(a));
  }
  if (j < 256){
    double a = -6.283185307179586476925286766559 * (double)j / 256.0;
    tw256[j] = make_float2((float)cos(a), (float)sin(a));
  }
}

// ---------------- GEMM: C[m][hw] = sum_t A[m][t]*(gz?gz[t]^4:1) * B[t][hw] ----------------
// Per-thread m-tile MT=32, grid (HW/256, 256/MT). A (scaled) staged in LDS, broadcast float4
// reads; B prefetched 8-deep in registers.
__global__ __launch_bounds__(256) void k_gemm(const float* __restrict__ A,
    const float* __restrict__ Bv, const float* __restrict__ gz, float* __restrict__ C){
  __shared__ float As[64][MT];   // [tt][mi], scaled by zz[t]
  __shared__ float zz[256];
  int tid = threadIdx.x;
  int hw = blockIdx.x*256 + tid;
  int m0 = blockIdx.y*MT;
  float acc[MT];
  #pragma unroll
  for (int i=0;i<MT;i++) acc[i]=0.f;
  {
    float s = 1.f;
    if (gz){ float g = gz[tid]; float g2=g*g; s = g2*g2; }
    zz[tid] = s;
  }
  for (int t0=0;t0<256;t0+=64){
    __syncthreads();
    #pragma unroll
    for (int e=0;e<(64*MT)/256;e++){
      int idx = e*256 + tid;
      int tt = idx >> 5, mi = idx & (MT-1);
      As[tt][mi] = A[(size_t)(m0+mi)*256 + t0 + tt] * zz[t0+tt];
    }
    __syncthreads();
    for (int ts=0;ts<64;ts+=8){
      float v[8];
      #pragma unroll
      for (int j=0;j<8;j++) v[j] = Bv[(size_t)(t0+ts+j)*HW + hw];
      #pragma unroll
      for (int j=0;j<8;j++){
        const float4* row = (const float4*)&As[ts+j][0];
        #pragma unroll
        for (int q=0;q<MT/4;q++){
          float4 a4 = row[q];
          acc[4*q+0] += a4.x*v[j]; acc[4*q+1] += a4.y*v[j];
          acc[4*q+2] += a4.z*v[j]; acc[4*q+3] += a4.w*v[j];
        }
      }
    }
  }
  #pragma unroll
  for (int mi=0;mi<MT;mi++) C[(size_t)(m0+mi)*HW + hw] = acc[mi];
}

// ---------------- Pass 1: R2C along x (zero-pad 128->256), lines (m<256, y<128) ----------------
__global__ __launch_bounds__(256) void k_fft_x_fwd(const float* __restrict__ tmp,
     float2* __restrict__ S, const float2* __restrict__ tw256){
  __shared__ float2 buf[16*LSTR256];
  int tid = threadIdx.x;
  int w = tid >> 4, b = tid & 15;
  int line = blockIdx.x*16 + w;       // 32768 lines
  int m = line >> 7, y = line & 127;
  float2* ln = buf + w*LSTR256;
  const float* src = tmp + (size_t)(m*128 + y)*128;
  #pragma unroll
  for (int a=0;a<16;a++){
    int n = 16*a + b;
    ln[n] = make_float2((n<128)? src[n] : 0.f, 0.f);
  }
  __syncthreads();
  fft256<-1>(ln, b, tw256);
  float2* dst = S + ((size_t)m*256 + y)*XP;
  #pragma unroll
  for (int a=0;a<8;a++){
    int k = 16*a + b;
    dst[k] = ln[k];
  }
  if (b==0) dst[128] = ln[128];
}

// ---------------- Pass 2: fwd along y (z<256), input y<128 nonzero, x<129 ----------------
__global__ __launch_bounds__(256) void k_fft_y_fwd(float2* __restrict__ S, const float2* __restrict__ tw256){
  __shared__ float2 buf[16*LSTR256];
  int tid = threadIdx.x;
  int w = tid & 15, b = tid >> 4;
  int z = blockIdx.x;               // 0..255
  int x = blockIdx.y*16 + w;        // up to 143
  bool act = (x < XS);
  float2* ln = buf + w*LSTR256;
  size_t base = ((size_t)z*256)*XP + x;
  #pragma unroll
  for (int a=0;a<8;a++){
    int n = 16*a + b;   // y 0..127
    ln[n] = act ? S[base + (size_t)n*XP] : make_float2(0.f,0.f);
    ln[n+128] = make_float2(0.f,0.f);
  }
  __syncthreads();
  fft256<-1>(ln, b, tw256);
  #pragma unroll
  for (int a=0;a<16;a++){
    int n = 16*a + b;
    if (act) S[base + (size_t)n*XP] = ln[n];
  }
}

// ---------------- Pass 3: fwd along z, L=512, input z<256 nonzero ----------------
__global__ __launch_bounds__(256) void k_fft_z_fwd(float2* __restrict__ S,
      const float2* __restrict__ tw256, const float2* __restrict__ tw512){
  __shared__ float2 buf[8*LSTR512];
  int tid = threadIdx.x;
  int w = tid & 7, lt = tid >> 3;
  int y = blockIdx.x;               // 0..255
  int x = blockIdx.y*8 + w;         // up to 135
  bool act = (x < XS);
  float2* ln = buf + w*LSTR512;
  size_t base = (size_t)y*XP + x;
  #pragma unroll
  for (int a=0;a<16;a++){
    int n = 32*a + lt;
    ln[n] = (act && n<256) ? S[base + (size_t)n*256*XP] : make_float2(0.f,0.f);
  }
  __syncthreads();
  fft512<-1,false>(ln, lt, tw256, tw512);
  #pragma unroll
  for (int a=0;a<16;a++){
    int n = 32*a + lt;
    if (act) S[base + (size_t)n*256*XP] = ln[n];
  }
}

// ---------------- Pass 4: pointwise Hermitian-symmetrized filter + 1/N ----------------
__global__ __launch_bounds__(256) void k_filter(float2* __restrict__ S, const float* __restrict__ R,
    const float* __restrict__ I, const float* __restrict__ w0, const float* __restrict__ w1){
  size_t idx = (size_t)blockIdx.x*256 + threadIdx.x;
  const size_t NPT = (size_t)Z2*Y2*XS;
  if (idx >= NPT) return;
  unsigned x  = (unsigned)(idx % XS);
  unsigned r2 = (unsigned)(idx / XS);
  unsigned ky = r2 & 255u;
  unsigned kz = r2 >> 8;
  unsigned mx = (256u - x) & 255u;
  unsigned my = (256u - ky) & 255u;
  unsigned mz = (512u - kz) & 511u;
  size_t ik  = ((size_t)kz*256 + ky)*256 + x;
  size_t imk = ((size_t)mz*256 + my)*256 + mx;
  float wr = R[ik] + 0.5f*(w0[ik] + w0[imk]);
  float wi = I[ik] + 0.5f*(w1[ik] - w1[imk]);
  const float sc = 1.f/33554432.f;   // 1/(512*256*256)
  wr *= sc; wi *= sc;
  size_t is = ((size_t)kz*256 + ky)*XP + x;
  float2 v = S[is];
  S[is] = make_float2(v.x*wr - v.y*wi, v.x*wi + v.y*wr);
}

// ---------------- Pass 5: inv along z, L=512, keep z<256 ----------------
__global__ __launch_bounds__(256) void k_fft_z_inv(float2* __restrict__ S,
      const float2* __restrict__ tw256, const float2* __restrict__ tw512){
  __shared__ float2 buf[8*LSTR512];
  int tid = threadIdx.x;
  int w = tid & 7, lt = tid >> 3;
  int y = blockIdx.x;
  int x = blockIdx.y*8 + w;
  bool act = (x < XS);
  float2* ln = buf + w*LSTR512;
  size_t base = (size_t)y*XP + x;
  #pragma unroll
  for (int a=0;a<16;a++){
    int n = 32*a + lt;
    ln[n] = act ? S[base + (size_t)n*256*XP] : make_float2(0.f,0.f);
  }
  __syncthreads();
  fft512<1,true>(ln, lt, tw256, tw512);
  #pragma unroll
  for (int a=0;a<8;a++){
    int n = 32*a + lt;   // 0..255
    if (act) S[base + (size_t)n*256*XP] = ln[n];
  }
}

// ---------------- Pass 6: inv along y (z<256), keep y<128 ----------------
__global__ __launch_bounds__(256) void k_fft_y_inv(float2* __restrict__ S, const float2* __restrict__ tw256){
  __shared__ float2 buf[16*LSTR256];
  int tid = threadIdx.x;
  int w = tid & 15, b = tid >> 4;
  int z = blockIdx.x;       // t 0..255
  int x = blockIdx.y*16 + w;
  bool act = (x < XS);
  float2* ln = buf + w*LSTR256;
  size_t base = ((size_t)z*256)*XP + x;
  #pragma unroll
  for (int a=0;a<16;a++){
    int n = 16*a + b;
    ln[n] = act ? S[base + (size_t)n*XP] : make_float2(0.f,0.f);
  }
  __syncthreads();
  fft256<1>(ln, b, tw256);
  #pragma unroll
  for (int a=0;a<8;a++){
    int n = 16*a + b;    // 0..127
    if (act) S[base + (size_t)n*XP] = ln[n];
  }
}

// ---------------- Pass 7: inv C2R along x, keep x<128, write real vol ----------------
__global__ __launch_bounds__(256) void k_fft_x_inv(const float2* __restrict__ S,
      float* __restrict__ vol, const float2* __restrict__ tw256){
  __shared__ float2 buf[16*LSTR256];
  int tid = threadIdx.x;
  int w = tid >> 4, b = tid & 15;
  int line = blockIdx.x*16 + w;   // t*128 + y
  int t = line >> 7, y = line & 127;
  float2* ln = buf + w*LSTR256;
  const float2* src = S + ((size_t)t*256 + y)*XP;
  #pragma unroll
  for (int a=0;a<8;a++){
    int k = 16*a + b;
    ln[k] = src[k];
  }
  if (b==0) ln[128] = src[128];
  __syncthreads();
  #pragma unroll
  for (int a=8;a<16;a++){
    int k = 16*a + b;     // 128..255
    if (k > 128){ float2 v = ln[256-k]; ln[k] = make_float2(v.x, -v.y); }
  }
  __syncthreads();
  fft256<1>(ln, b, tw256);
  float* dst = vol + (size_t)(t*128 + y)*128;
  #pragma unroll
  for (int a=0;a<8;a++){
    int n = 16*a + b;
    dst[n] = ln[n].x;
  }
}

extern "C" void kernel_launch(void* const* d_in, const int* in_sizes, int n_in,
                              void* d_out, int out_size, void* d_ws, size_t ws_size,
                              hipStream_t stream) {
  const float* fet = (const float*)d_in[0];           // (1,1,256,128,128)
  const float* gz  = (const float*)d_in[1];           // (1,256,1,1)
  const float* mtx = (const float*)d_in[2];           // (256,256)
  const float* mtxi= (const float*)d_in[3];           // (256,256)
  const float* Rr  = (const float*)d_in[4];           // (512,256,256)
  const float* Ii  = (const float*)d_in[5];           // (512,256,256)
  const float* lw  = (const float*)d_in[6];           // (2,512,256,256)
  const float* w0  = lw;
  const float* w1  = lw + (size_t)Z2*Y2*X2;
  float* out = (float*)d_out;

  char* ws = (char*)d_ws;
  const size_t OFF_TW256 = 0;
  const size_t OFF_TW512 = 2048;
  const size_t OFF_S     = 8192;
  const size_t S_BYTES   = (size_t)Z2*Y2*XP*sizeof(float2);   // 136,314,880
  const size_t OFF_TMP   = OFF_S + S_BYTES;
  const size_t OFF_VOL   = OFF_TMP + (size_t)TC*HW*sizeof(float);
  const size_t NEED      = OFF_VOL + (size_t)TC*HW*sizeof(float);
  if (ws_size < NEED) return;   // diagnostic: leaves d_out zero

  float2* tw256 = (float2*)(ws + OFF_TW256);
  float2* tw512 = (float2*)(ws + OFF_TW512);
  float2* S     = (float2*)(ws + OFF_S);
  float*  tmp   = (float*)(ws + OFF_TMP);
  float*  vol   = (float*)(ws + OFF_VOL);

  hipLaunchKernelGGL(k_init_tw, dim3(1), dim3(512), 0, stream, tw256, tw512);
  hipLaunchKernelGGL(k_gemm, dim3(64,256/MT), dim3(256), 0, stream, mtx, fet, gz, tmp);
  hipLaunchKernelGGL(k_fft_x_fwd, dim3(2048), dim3(256), 0, stream, tmp, S, tw256);
  hipLaunchKernelGGL(k_fft_y_fwd, dim3(256,9), dim3(256), 0, stream, S, tw256);
  hipLaunchKernelGGL(k_fft_z_fwd, dim3(256,17), dim3(256), 0, stream, S, tw256, tw512);
  hipLaunchKernelGGL(k_filter, dim3(66048), dim3(256), 0, stream, S, Rr, Ii, w0, w1);
  hipLaunchKernelGGL(k_fft_z_inv, dim3(256,17), dim3(256), 0, stream, S, tw256, tw512);
  hipLaunchKernelGGL(k_fft_y_inv, dim3(256,9), dim3(256), 0, stream, S, tw256);
  hipLaunchKernelGGL(k_fft_x_inv, dim3(2048), dim3(256), 0, stream, S, vol, tw256);
  hipLaunchKernelGGL(k_gemm, dim3(64,256/MT), dim3(256), 0, stream, mtxi, vol, (const float*)nullptr, out);
}